// Round 2
// baseline (175.234 us; speedup 1.0000x reference)
//
#include <hip/hip_runtime.h>
#include <hip/hip_bf16.h>

// Problem constants
constexpr int N    = 2048;
constexpr int IN   = 256;
constexpr int OUT  = 512;
constexpr int NH   = 8;
constexpr int HD   = 64;      // OUT / NH
constexpr int NC   = 16;      // key chunks for attention
constexpr int KPB  = N / NC;  // 128 keys per chunk
constexpr int KT   = KPB / 16;// 8 key-tiles of 16

typedef _Float16  f16x8  __attribute__((ext_vector_type(8)));
typedef float     f32x4  __attribute__((ext_vector_type(4)));

#if __has_builtin(__builtin_amdgcn_exp2f)
#define EXP2(x) __builtin_amdgcn_exp2f(x)
#else
#define EXP2(x) exp2f(x)
#endif

// Q is pre-scaled by 1/sqrt(64) * log2(e) so attention uses raw exp2.
#define QSCALE (0.125f * 1.44269504088896f)

// ---------------------------------------------------------------------------
// Kernel 1: fused Q/K GEMM + vpm (motion-gated V.Wo projection).
//   blocks 0..511 : fp16 MFMA GEMM, A = x (f32->f16 inline),
//                   B = W columns read directly (f32->f16 inline, L2-resident).
//                   Output head-major fp16 Qh/Kh (Q scaled by QSCALE, +bias).
//   blocks 512..575: compute Wvo/bvo in-LDS, then
//                   vpmT[h][k] = sigmoid(mg(k)) * (x[k] @ Wvo[:,h] + bvo[h]).
//   block 512 also zeroes the finalize counters.
// ---------------------------------------------------------------------------
__global__ __launch_bounds__(256)
void fused_qk_vpm(const float* __restrict__ x,
                  const float* __restrict__ Wq, const float* __restrict__ bq,
                  const float* __restrict__ Wk, const float* __restrict__ bk,
                  const float* __restrict__ Wv, const float* __restrict__ bv,
                  const float* __restrict__ Wo,
                  const float* __restrict__ rel_vel, const float* __restrict__ rel_angle,
                  const float* __restrict__ Wmg1, const float* __restrict__ bmg1,
                  const float* __restrict__ Wmg2, const float* __restrict__ bmg2,
                  _Float16* __restrict__ Qh, _Float16* __restrict__ Kh,
                  float* __restrict__ vpmT,
                  unsigned* __restrict__ counters) {
    __shared__ float smem[2568];   // vpm: wo_s(512)+wvo_s(2048)+bvo_s(8); gemm: stage alias
    const int tid = threadIdx.x;

    if (blockIdx.x >= 512) {
        // ================= vpm branch =================
        float* wo_s  = smem;          // 512
        float* wvo_s = smem + 512;    // 2048, layout [i][h]
        float* bvo_s = smem + 2560;   // 8
        wo_s[tid]       = Wo[tid];
        wo_s[tid + 256] = Wo[tid + 256];
        if (blockIdx.x == 512 && tid < 8) counters[tid] = 0u;
        __syncthreads();

        // Wvo[i][h] = sum_d Wv[i][h*64+d] * Wo[h*64+d]  (8 entries/thread)
        #pragma unroll
        for (int rep = 0; rep < 8; rep++) {
            const int idx = rep * 256 + tid;
            const int i = idx >> 3, h = idx & 7;
            const float* wr = Wv + (size_t)i * OUT + h * HD;
            const float* wo = wo_s + h * HD;
            float s = 0.f;
            #pragma unroll
            for (int d = 0; d < HD; d += 4) {
                const float4 v = *(const float4*)(wr + d);
                s += v.x * wo[d + 0] + v.y * wo[d + 1]
                   + v.z * wo[d + 2] + v.w * wo[d + 3];
            }
            wvo_s[i * NH + h] = s;
        }
        if (tid < NH) {
            const float* wo = wo_s + tid * HD;
            float sb = 0.f;
            #pragma unroll
            for (int d = 0; d < HD; d++) sb += bv[tid * HD + d] * wo[d];
            bvo_s[tid] = sb;
        }
        __syncthreads();

        const int k = (blockIdx.x - 512) * 32 + (tid >> 3);
        const int h = tid & 7;

        const float m0 = rel_vel[k], m1 = rel_angle[k];
        float g = bmg2[0];
        #pragma unroll
        for (int j = 0; j < HD; j++) {
            float t = m0 * Wmg1[j] + m1 * Wmg1[HD + j] + bmg1[j];
            t = fmaxf(t, 0.f);
            g += t * Wmg2[j];
        }
        const float mg = 1.f / (1.f + __expf(-g));

        const float4* xr = (const float4*)(x + (size_t)k * IN);
        float a0 = 0.f, a1 = 0.f, a2 = 0.f, a3 = 0.f;
        #pragma unroll 4
        for (int i = 0; i < IN / 4; i++) {
            const float4 v = xr[i];
            a0 += v.x * wvo_s[(i * 4 + 0) * NH + h];
            a1 += v.y * wvo_s[(i * 4 + 1) * NH + h];
            a2 += v.z * wvo_s[(i * 4 + 2) * NH + h];
            a3 += v.w * wvo_s[(i * 4 + 3) * NH + h];
        }
        vpmT[h * N + k] = mg * (a0 + a1 + a2 + a3 + bvo_s[h]);
        return;
    }

    // ================= gemm branch =================
    const int lane  = tid & 63;
    const int wave  = tid >> 6;
    const int row16 = lane & 15;
    const int quad  = lane >> 4;
    const int nb0 = (blockIdx.x & 7) * 128;
    const int mb  = (blockIdx.x >> 3) * 32;
    const bool isQ = (nb0 < OUT);                 // block-uniform
    const float* Wsel = isQ ? Wq : Wk;
    const int ncb = (isQ ? nb0 : nb0 - OUT) + wave * 32 + row16;

    const float* xr0 = x + (size_t)(mb + row16) * IN;
    const float* xr1 = x + (size_t)(mb + 16 + row16) * IN;

    f32x4 acc[2][2] = {};
    for (int k0 = 0; k0 < IN; k0 += 32) {
        const int ko = k0 + quad * 8;
        f16x8 a[2], bf[2];
        {
            const float4 u0 = *(const float4*)(xr0 + ko);
            const float4 u1 = *(const float4*)(xr0 + ko + 4);
            a[0][0] = (_Float16)u0.x; a[0][1] = (_Float16)u0.y;
            a[0][2] = (_Float16)u0.z; a[0][3] = (_Float16)u0.w;
            a[0][4] = (_Float16)u1.x; a[0][5] = (_Float16)u1.y;
            a[0][6] = (_Float16)u1.z; a[0][7] = (_Float16)u1.w;
            const float4 v0 = *(const float4*)(xr1 + ko);
            const float4 v1 = *(const float4*)(xr1 + ko + 4);
            a[1][0] = (_Float16)v0.x; a[1][1] = (_Float16)v0.y;
            a[1][2] = (_Float16)v0.z; a[1][3] = (_Float16)v0.w;
            a[1][4] = (_Float16)v1.x; a[1][5] = (_Float16)v1.y;
            a[1][6] = (_Float16)v1.z; a[1][7] = (_Float16)v1.w;
        }
        // B[n][k] fragment = W[k][n] column reads; for fixed j the 16 lanes of a
        // quad read 16 consecutive floats -> coalesced 64B segments, L2-hit.
        #pragma unroll
        for (int nt = 0; nt < 2; nt++) {
            const float* wp = Wsel + (size_t)ko * OUT + ncb + nt * 16;
            f16x8 b;
            #pragma unroll
            for (int j = 0; j < 8; j++) b[j] = (_Float16)wp[(size_t)j * OUT];
            bf[nt] = b;
        }
        #pragma unroll
        for (int mt = 0; mt < 2; mt++)
            #pragma unroll
            for (int nt = 0; nt < 2; nt++)
                acc[mt][nt] = __builtin_amdgcn_mfma_f32_16x16x32_f16(a[mt], bf[nt], acc[mt][nt], 0, 0, 0);
    }

    // stage into LDS (C layout: col n = lane&15, row m = quad*4+r)
    _Float16* stage = (_Float16*)smem;            // 32*132 f16 = 8448 B
    const float scale = isQ ? QSCALE : 1.0f;
    #pragma unroll
    for (int mt = 0; mt < 2; mt++)
        #pragma unroll
        for (int nt = 0; nt < 2; nt++) {
            const int nl = wave * 32 + nt * 16 + row16;   // 0..127
            const int np = nb0 + nl;
            const int nq = isQ ? np : np - OUT;
            const float bias = isQ ? bq[nq] : bk[nq];
            #pragma unroll
            for (int r = 0; r < 4; r++) {
                const int ml = mt * 16 + quad * 4 + r;    // 0..31
                stage[ml * 132 + nl] = (_Float16)((acc[mt][nt][r] + bias) * scale);
            }
        }
    __syncthreads();

    // write out full lines: 64 rows (2 heads x 32 m) x 128B each
    _Float16* dst = isQ ? Qh : Kh;
    const int r2   = tid >> 2;         // 0..63
    const int cidx = tid & 3;          // 32B chunk
    const int hl   = r2 >> 5;          // head within block
    const int m    = r2 & 31;
    const int nqh  = (isQ ? nb0 : nb0 - OUT) + hl * 64;
    const int h    = nqh >> 6;
    const size_t goff = ((size_t)h * N + mb + m) * HD + cidx * 16;
    const int soff = m * 132 + hl * 64 + cidx * 16;
    *(f16x8*)(dst + goff)     = *(const f16x8*)(&stage[soff]);
    *(f16x8*)(dst + goff + 8) = *(const f16x8*)(&stage[soff + 8]);
}

// ---------------------------------------------------------------------------
// Kernel 2: attention partials + fused last-block finalize.
// Wave = 64 q x 128 k for one head; block = 4 waves; grid 1024:
// h = b&7 (XCD pin), then c (16) x qg (8).
// After partial write: __threadfence + atomicAdd(counters[qg]); the 128th
// (last) block for that q-group reproduces the old finalize kernel exactly:
// out[q] = bo + sum_h (sum_c num)/(sum_c den) for its 256 q's (plain store).
// ---------------------------------------------------------------------------
__global__ __launch_bounds__(256)
void attn_fin(const _Float16* __restrict__ Qh, const _Float16* __restrict__ Kh,
              const float* __restrict__ vpmT, const float* __restrict__ bo,
              float* __restrict__ pnum, float* __restrict__ pden,
              unsigned* __restrict__ counters, float* __restrict__ out) {
    const int b = blockIdx.x;
    const int h = b & 7;
    const int r = b >> 3;             // 0..127
    const int c = r >> 3;             // key chunk 0..15
    const int qg = r & 7;             // q-group 0..7
    const int lane = threadIdx.x & 63;
    const int wave = threadIdx.x >> 6;
    const int q0 = (qg * 4 + wave) * 64;
    const int row16 = lane & 15;
    const int quad  = lane >> 4;

    // B fragments (Q): B[n=lane&15][k=quad*8+j]; 4 q-tiles x 2 d-halves
    f16x8 Bq[4][2];
    #pragma unroll
    for (int qt = 0; qt < 4; qt++) {
        const size_t qoff = ((size_t)h * N + q0 + qt * 16 + row16) * HD + quad * 8;
        Bq[qt][0] = *(const f16x8*)(Qh + qoff);
        Bq[qt][1] = *(const f16x8*)(Qh + qoff + 32);
    }

    float num[4] = {}, den[4] = {};
    const int k0 = c * KPB;
    const size_t kbase = ((size_t)h * N + k0 + row16) * HD + quad * 8;
    const float* vp = vpmT + h * N + k0 + quad * 4;

    // register double-buffer the K tile + vpm
    f16x8 A0 = *(const f16x8*)(Kh + kbase);
    f16x8 A1 = *(const f16x8*)(Kh + kbase + 32);
    f32x4 vv = *(const f32x4*)(vp);

    #pragma unroll
    for (int t = 0; t < KT; t++) {
        const int tn = (t + 1 < KT) ? t + 1 : t;
        const size_t ka = kbase + (size_t)tn * 16 * HD;
        const f16x8 nA0 = *(const f16x8*)(Kh + ka);
        const f16x8 nA1 = *(const f16x8*)(Kh + ka + 32);
        const f32x4 nvv = *(const f32x4*)(vp + tn * 16);

        #pragma unroll
        for (int qt = 0; qt < 4; qt++) {
            f32x4 s = {0.f, 0.f, 0.f, 0.f};
            s = __builtin_amdgcn_mfma_f32_16x16x32_f16(A0, Bq[qt][0], s, 0, 0, 0);
            s = __builtin_amdgcn_mfma_f32_16x16x32_f16(A1, Bq[qt][1], s, 0, 0, 0);
            #pragma unroll
            for (int r4 = 0; r4 < 4; r4++) {
                const float e = EXP2(s[r4]);          // key = k0+t*16+quad*4+r4
                num[qt] += e * vv[r4];
                den[qt] += e;
            }
        }
        A0 = nA0; A1 = nA1; vv = nvv;
    }

    // reduce over quads (keys live on the quad dimension)
    #pragma unroll
    for (int qt = 0; qt < 4; qt++) {
        float n = num[qt], d = den[qt];
        n += __shfl_xor(n, 16, 64);  d += __shfl_xor(d, 16, 64);
        n += __shfl_xor(n, 32, 64);  d += __shfl_xor(d, 32, 64);
        if (quad == 0) {
            const int q = q0 + qt * 16 + row16;
            pnum[((size_t)c * NH + h) * N + q] = n;
            pden[((size_t)c * NH + h) * N + q] = d;
        }
    }

    // -------- fused finalize: last of the 128 blocks per q-group --------
    __syncthreads();                       // block's partial stores ordered
    __shared__ int last;
    if (threadIdx.x == 0) {
        __threadfence();                   // release: partials visible device-wide
        last = (atomicAdd(&counters[qg], 1u) == (unsigned)(NC * NH - 1));
    }
    __syncthreads();
    if (last) {
        __threadfence();                   // acquire before reading others' partials
        const int q = qg * 256 + (int)threadIdx.x;
        float acc = bo[0];
        #pragma unroll
        for (int hh = 0; hh < NH; hh++) {
            float n = 0.f, d = 0.f;
            #pragma unroll
            for (int ci = 0; ci < NC; ci++) {
                n += pnum[((size_t)ci * NH + hh) * N + q];
                d += pden[((size_t)ci * NH + hh) * N + q];
            }
            acc += n / d;
        }
        out[q] = acc;                      // plain store, exact old-finalize math
    }
}

// ---------------------------------------------------------------------------
extern "C" void kernel_launch(void* const* d_in, const int* in_sizes, int n_in,
                              void* d_out, int out_size, void* d_ws, size_t ws_size,
                              hipStream_t stream) {
    const float* x         = (const float*)d_in[0];
    // d_in[1] = rel_pos (unused: per-query bias cancels in softmax)
    const float* rel_vel   = (const float*)d_in[2];
    const float* rel_angle = (const float*)d_in[3];
    const float* Wq        = (const float*)d_in[4];
    const float* bq        = (const float*)d_in[5];
    const float* Wk        = (const float*)d_in[6];
    const float* bk        = (const float*)d_in[7];
    const float* Wv        = (const float*)d_in[8];
    const float* bv        = (const float*)d_in[9];
    // d_in[10..13] = Wsb1,bsb1,Wsb2,bsb2 (unused)
    const float* Wmg1      = (const float*)d_in[14];
    const float* bmg1      = (const float*)d_in[15];
    const float* Wmg2      = (const float*)d_in[16];
    const float* bmg2      = (const float*)d_in[17];
    const float* Wo        = (const float*)d_in[18];
    const float* bo        = (const float*)d_in[19];
    float* out = (float*)d_out;

    // workspace layout
    _Float16* Qh   = (_Float16*)d_ws;                    // [NH][N][HD]
    _Float16* Kh   = Qh + (size_t)NH * N * HD;
    float* vpmT    = (float*)(Kh + (size_t)NH * N * HD); // NH*N
    float* pnum    = vpmT + (size_t)NH * N;              // NC*NH*N
    float* pden    = pnum + (size_t)NC * NH * N;         // NC*NH*N
    unsigned* counters = (unsigned*)(pden + (size_t)NC * NH * N); // 8

    hipLaunchKernelGGL(fused_qk_vpm, dim3(576), dim3(256), 0, stream,
                       x, Wq, bq, Wk, bk, Wv, bv, Wo,
                       rel_vel, rel_angle, Wmg1, bmg1, Wmg2, bmg2,
                       Qh, Kh, vpmT, counters);
    hipLaunchKernelGGL(attn_fin, dim3(1024), dim3(256), 0, stream,
                       Qh, Kh, vpmT, bo, pnum, pden, counters, out);
}

// Round 3
// 160.198 us; speedup vs baseline: 1.0939x; 1.0939x over previous
//
#include <hip/hip_runtime.h>
#include <hip/hip_bf16.h>

// Problem constants
constexpr int N    = 2048;
constexpr int IN   = 256;
constexpr int OUT  = 512;
constexpr int NH   = 8;
constexpr int HD   = 64;      // OUT / NH
constexpr int NQK  = 1024;    // Q|K concatenated columns
constexpr int KT   = 8;       // 8 key-tiles of 16 per wave (128 keys)

typedef _Float16  f16x8  __attribute__((ext_vector_type(8)));
typedef _Float16  f16x4  __attribute__((ext_vector_type(4)));
typedef float     f32x4  __attribute__((ext_vector_type(4)));

#if __has_builtin(__builtin_amdgcn_exp2f)
#define EXP2(x) __builtin_amdgcn_exp2f(x)
#else
#define EXP2(x) exp2f(x)
#endif

// Q is pre-scaled by 1/sqrt(64) * log2(e) so attention uses raw exp2.
#define QSCALE (0.125f * 1.44269504088896f)

// ---------------------------------------------------------------------------
// Kernel 1: prep.
//   blocks 0..255 : WT[n'][k] = fp16 transpose of [Wq|Wk]  (32n x 32k tiles)
//   blocks 256..319: vpmT[h][k] = sigmoid(mg(k)) * (x[k] @ Wvo[:,h] + bvo[h])
//                    (Wvo/bvo recomputed per-block in LDS, dependency-free)
//   block 256 also pre-inits out[q] = bo[0].
// ---------------------------------------------------------------------------
__global__ __launch_bounds__(256)
void prep_wt_vpm(const float* __restrict__ Wq, const float* __restrict__ Wk,
                 const float* __restrict__ Wv, const float* __restrict__ bv,
                 const float* __restrict__ Wo, const float* __restrict__ bo,
                 const float* __restrict__ x,
                 const float* __restrict__ rel_vel, const float* __restrict__ rel_angle,
                 const float* __restrict__ Wmg1, const float* __restrict__ bmg1,
                 const float* __restrict__ Wmg2, const float* __restrict__ bmg2,
                 _Float16* __restrict__ WT, float* __restrict__ vpmT,
                 float* __restrict__ out) {
    __shared__ float smem[2568];
    const int tid = threadIdx.x;
    const int b = blockIdx.x;

    if (b < 256) {
        // ---- WT transpose via LDS 32x32 tile ----
        const int k0 = (b & 7) * 32;         // k tile
        const int n0 = (b >> 3) * 32;        // n' tile (never straddles 512)
        const float* W = (n0 < OUT) ? Wq : Wk;
        const int nc = (n0 < OUT) ? n0 : n0 - OUT;
        {
            const int row = tid >> 3;          // k within tile
            const int c4  = (tid & 7) * 4;     // n within tile
            const float4 v = *(const float4*)(W + (size_t)(k0 + row) * OUT + nc + c4);
            smem[row * 33 + c4 + 0] = v.x;
            smem[row * 33 + c4 + 1] = v.y;
            smem[row * 33 + c4 + 2] = v.z;
            smem[row * 33 + c4 + 3] = v.w;
        }
        __syncthreads();
        {
            const int nrow = tid >> 3;         // n within tile
            const int k4   = (tid & 7) * 4;    // k within tile
            f16x4 o;
            #pragma unroll
            for (int j = 0; j < 4; j++)
                o[j] = (_Float16)smem[(k4 + j) * 33 + nrow];
            *(f16x4*)(WT + (size_t)(n0 + nrow) * IN + k0 + k4) = o;
        }
        return;
    }

    // ================= vpm branch =================
    float* wo_s  = smem;          // 512
    float* wvo_s = smem + 512;    // 2048, layout [i][h]
    float* bvo_s = smem + 2560;   // 8
    wo_s[tid]       = Wo[tid];
    wo_s[tid + 256] = Wo[tid + 256];
    if (b == 256) {
        const float b0 = bo[0];
        #pragma unroll
        for (int q = tid; q < N; q += 256) out[q] = b0;
    }
    __syncthreads();

    // Wvo[i][h] = sum_d Wv[i][h*64+d] * Wo[h*64+d]  (8 entries/thread)
    #pragma unroll
    for (int rep = 0; rep < 8; rep++) {
        const int idx = rep * 256 + tid;
        const int i = idx >> 3, h = idx & 7;
        const float* wr = Wv + (size_t)i * OUT + h * HD;
        const float* wo = wo_s + h * HD;
        float s = 0.f;
        #pragma unroll
        for (int d = 0; d < HD; d += 4) {
            const float4 v = *(const float4*)(wr + d);
            s += v.x * wo[d + 0] + v.y * wo[d + 1]
               + v.z * wo[d + 2] + v.w * wo[d + 3];
        }
        wvo_s[i * NH + h] = s;
    }
    if (tid < NH) {
        const float* wo = wo_s + tid * HD;
        float sb = 0.f;
        #pragma unroll
        for (int d = 0; d < HD; d++) sb += bv[tid * HD + d] * wo[d];
        bvo_s[tid] = sb;
    }
    __syncthreads();

    const int k = (b - 256) * 32 + (tid >> 3);
    const int h = tid & 7;

    const float m0 = rel_vel[k], m1 = rel_angle[k];
    float g = bmg2[0];
    #pragma unroll
    for (int j = 0; j < HD; j++) {
        float t = m0 * Wmg1[j] + m1 * Wmg1[HD + j] + bmg1[j];
        t = fmaxf(t, 0.f);
        g += t * Wmg2[j];
    }
    const float mg = 1.f / (1.f + __expf(-g));

    const float4* xr = (const float4*)(x + (size_t)k * IN);
    float a0 = 0.f, a1 = 0.f, a2 = 0.f, a3 = 0.f;
    #pragma unroll 4
    for (int i = 0; i < IN / 4; i++) {
        const float4 v = xr[i];
        a0 += v.x * wvo_s[(i * 4 + 0) * NH + h];
        a1 += v.y * wvo_s[(i * 4 + 1) * NH + h];
        a2 += v.z * wvo_s[(i * 4 + 2) * NH + h];
        a3 += v.w * wvo_s[(i * 4 + 3) * NH + h];
    }
    vpmT[h * N + k] = mg * (a0 + a1 + a2 + a3 + bvo_s[h]);
}

// ---------------------------------------------------------------------------
// Kernel 2: Q/K projection GEMM, fp16 MFMA.
// 1024 blocks x 256 thr: tile 32m x 64n (one head per tile), 4 waves of 16n.
// A = x rows (f32 -> f16 inline, coalesced), B = WT rows (f16, coalesced).
// 4 blocks/CU -> 4 waves/SIMD for latency hiding.
// ---------------------------------------------------------------------------
__global__ __launch_bounds__(256)
void gemm_qk(const float* __restrict__ x, const _Float16* __restrict__ WT,
             const float* __restrict__ bq, const float* __restrict__ bk,
             _Float16* __restrict__ Qh, _Float16* __restrict__ Kh) {
    __shared__ _Float16 stage[32 * 68];
    const int tid = threadIdx.x;
    const int lane  = tid & 63;
    const int wave  = tid >> 6;
    const int row16 = lane & 15;
    const int quad  = lane >> 4;

    const int gn = (blockIdx.x & 15) * 64;   // global n' tile (one head)
    const int mb = (blockIdx.x >> 4) * 32;   // m tile
    const bool isQ = (gn < OUT);

    const float* xr0 = x + (size_t)(mb + row16) * IN;
    const float* xr1 = xr0 + (size_t)16 * IN;
    const _Float16* wrow = WT + (size_t)(gn + wave * 16 + row16) * IN;

    f32x4 acc[2] = {};
    for (int k0 = 0; k0 < IN; k0 += 32) {
        const int ko = k0 + quad * 8;
        f16x8 a[2];
        {
            const float4 u0 = *(const float4*)(xr0 + ko);
            const float4 u1 = *(const float4*)(xr0 + ko + 4);
            a[0][0] = (_Float16)u0.x; a[0][1] = (_Float16)u0.y;
            a[0][2] = (_Float16)u0.z; a[0][3] = (_Float16)u0.w;
            a[0][4] = (_Float16)u1.x; a[0][5] = (_Float16)u1.y;
            a[0][6] = (_Float16)u1.z; a[0][7] = (_Float16)u1.w;
            const float4 v0 = *(const float4*)(xr1 + ko);
            const float4 v1 = *(const float4*)(xr1 + ko + 4);
            a[1][0] = (_Float16)v0.x; a[1][1] = (_Float16)v0.y;
            a[1][2] = (_Float16)v0.z; a[1][3] = (_Float16)v0.w;
            a[1][4] = (_Float16)v1.x; a[1][5] = (_Float16)v1.y;
            a[1][6] = (_Float16)v1.z; a[1][7] = (_Float16)v1.w;
        }
        const f16x8 bf = *(const f16x8*)(wrow + ko);
        acc[0] = __builtin_amdgcn_mfma_f32_16x16x32_f16(a[0], bf, acc[0], 0, 0, 0);
        acc[1] = __builtin_amdgcn_mfma_f32_16x16x32_f16(a[1], bf, acc[1], 0, 0, 0);
    }

    // stage into LDS (C layout: col n = lane&15, row m = quad*4+r)
    const float scale = isQ ? QSCALE : 1.0f;
    const int nl = wave * 16 + row16;              // 0..63
    const int nq = (isQ ? gn : gn - OUT) + nl;
    const float bias = isQ ? bq[nq] : bk[nq];
    #pragma unroll
    for (int mt = 0; mt < 2; mt++)
        #pragma unroll
        for (int r = 0; r < 4; r++) {
            const int ml = mt * 16 + quad * 4 + r; // 0..31
            stage[ml * 68 + nl] = (_Float16)((acc[mt][r] + bias) * scale);
        }
    __syncthreads();

    // write out: 32 rows x 64 f16 (one head), 8 chunks of 16B per row
    _Float16* dst = isQ ? Qh : Kh;
    const int h = (isQ ? gn : gn - OUT) >> 6;
    const int r = tid >> 3;            // 0..31
    const int c = tid & 7;             // 0..7
    const size_t goff = ((size_t)h * N + mb + r) * HD + c * 8;
    *(f16x8*)(dst + goff) = *(const f16x8*)(&stage[r * 68 + c * 8]);
}

// ---------------------------------------------------------------------------
// Kernel 3: attention, self-contained (no partials, no fences, no finalize).
// 256 blocks x 1024 thr: block = (head h = b&7, 64-q tile qg = b>>3).
// 16 waves split the 2048 keys (128 each, same inner loop as before).
// Cross-wave reduce in LDS (same order as old finalize's ci loop), then
// atomicAdd(out + q, num/den).  out pre-initialized to bo[0] in kernel 1.
// ---------------------------------------------------------------------------
__global__ __launch_bounds__(1024)
void attn_out(const _Float16* __restrict__ Qh, const _Float16* __restrict__ Kh,
              const float* __restrict__ vpmT, float* __restrict__ out) {
    __shared__ float sn[16 * 64];
    __shared__ float sd[16 * 64];
    const int b = blockIdx.x;
    const int h  = b & 7;              // head == XCD id under round-robin
    const int qg = b >> 3;             // 0..31
    const int tid  = threadIdx.x;
    const int wave = tid >> 6;         // 0..15: key-split
    const int lane = tid & 63;
    const int row16 = lane & 15;
    const int quad  = lane >> 4;
    const int q0 = qg * 64;

    // B fragments (Q): B[n=lane&15][k=quad*8+j]; 4 q-tiles x 2 d-halves
    f16x8 Bq[4][2];
    #pragma unroll
    for (int qt = 0; qt < 4; qt++) {
        const size_t qoff = ((size_t)h * N + q0 + qt * 16 + row16) * HD + quad * 8;
        Bq[qt][0] = *(const f16x8*)(Qh + qoff);
        Bq[qt][1] = *(const f16x8*)(Qh + qoff + 32);
    }

    float num[4] = {}, den[4] = {};
    const int k0 = wave * 128;
    const size_t kbase = ((size_t)h * N + k0 + row16) * HD + quad * 8;
    const float* vp = vpmT + h * N + k0 + quad * 4;

    // register double-buffer the K tile + vpm
    f16x8 A0 = *(const f16x8*)(Kh + kbase);
    f16x8 A1 = *(const f16x8*)(Kh + kbase + 32);
    f32x4 vv = *(const f32x4*)(vp);

    #pragma unroll
    for (int t = 0; t < KT; t++) {
        const int tn = (t + 1 < KT) ? t + 1 : t;
        const size_t ka = kbase + (size_t)tn * 16 * HD;
        const f16x8 nA0 = *(const f16x8*)(Kh + ka);
        const f16x8 nA1 = *(const f16x8*)(Kh + ka + 32);
        const f32x4 nvv = *(const f32x4*)(vp + tn * 16);

        #pragma unroll
        for (int qt = 0; qt < 4; qt++) {
            f32x4 s = {0.f, 0.f, 0.f, 0.f};
            s = __builtin_amdgcn_mfma_f32_16x16x32_f16(A0, Bq[qt][0], s, 0, 0, 0);
            s = __builtin_amdgcn_mfma_f32_16x16x32_f16(A1, Bq[qt][1], s, 0, 0, 0);
            #pragma unroll
            for (int r4 = 0; r4 < 4; r4++) {
                const float e = EXP2(s[r4]);          // key = k0+t*16+quad*4+r4
                num[qt] += e * vv[r4];
                den[qt] += e;
            }
        }
        A0 = nA0; A1 = nA1; vv = nvv;
    }

    // reduce over quads (keys live on the quad dimension)
    #pragma unroll
    for (int qt = 0; qt < 4; qt++) {
        float n = num[qt], d = den[qt];
        n += __shfl_xor(n, 16, 64);  d += __shfl_xor(d, 16, 64);
        n += __shfl_xor(n, 32, 64);  d += __shfl_xor(d, 32, 64);
        if (quad == 0) {
            sn[wave * 64 + qt * 16 + row16] = n;
            sd[wave * 64 + qt * 16 + row16] = d;
        }
    }
    __syncthreads();

    // cross-wave reduce (ascending wave = old finalize's ascending-ci order)
    if (tid < 64) {
        float n = 0.f, d = 0.f;
        #pragma unroll
        for (int w = 0; w < 16; w++) {
            n += sn[w * 64 + tid];
            d += sd[w * 64 + tid];
        }
        atomicAdd(out + q0 + tid, n / d);
    }
}

// ---------------------------------------------------------------------------
extern "C" void kernel_launch(void* const* d_in, const int* in_sizes, int n_in,
                              void* d_out, int out_size, void* d_ws, size_t ws_size,
                              hipStream_t stream) {
    const float* x         = (const float*)d_in[0];
    // d_in[1] = rel_pos (unused: per-query bias cancels in softmax)
    const float* rel_vel   = (const float*)d_in[2];
    const float* rel_angle = (const float*)d_in[3];
    const float* Wq        = (const float*)d_in[4];
    const float* bq        = (const float*)d_in[5];
    const float* Wk        = (const float*)d_in[6];
    const float* bk        = (const float*)d_in[7];
    const float* Wv        = (const float*)d_in[8];
    const float* bv        = (const float*)d_in[9];
    // d_in[10..13] = Wsb1,bsb1,Wsb2,bsb2 (unused)
    const float* Wmg1      = (const float*)d_in[14];
    const float* bmg1      = (const float*)d_in[15];
    const float* Wmg2      = (const float*)d_in[16];
    const float* bmg2      = (const float*)d_in[17];
    const float* Wo        = (const float*)d_in[18];
    const float* bo        = (const float*)d_in[19];
    float* out = (float*)d_out;

    // workspace layout
    _Float16* WT  = (_Float16*)d_ws;                     // NQK*IN
    _Float16* Qh  = WT + (size_t)NQK * IN;               // [NH][N][HD]
    _Float16* Kh  = Qh + (size_t)NH * N * HD;
    float* vpmT   = (float*)(Kh + (size_t)NH * N * HD);  // NH*N

    hipLaunchKernelGGL(prep_wt_vpm, dim3(320), dim3(256), 0, stream,
                       Wq, Wk, Wv, bv, Wo, bo, x, rel_vel, rel_angle,
                       Wmg1, bmg1, Wmg2, bmg2, WT, vpmT, out);
    hipLaunchKernelGGL(gemm_qk, dim3(1024), dim3(256), 0, stream,
                       x, WT, bq, bk, Qh, Kh);
    hipLaunchKernelGGL(attn_out, dim3(256), dim3(1024), 0, stream,
                       Qh, Kh, vpmT, out);
}

// Round 4
// 141.889 us; speedup vs baseline: 1.2350x; 1.1290x over previous
//
#include <hip/hip_runtime.h>
#include <hip/hip_bf16.h>

// Problem constants
constexpr int N    = 2048;
constexpr int IN   = 256;
constexpr int OUT  = 512;
constexpr int NH   = 8;
constexpr int HD   = 64;      // OUT / NH
constexpr int NQK  = 1024;    // Q|K concatenated columns
constexpr int NC   = 16;      // key chunks for attention
constexpr int KPB  = N / NC;  // 128 keys per chunk
constexpr int KT   = KPB / 16;// 8 key-tiles of 16

typedef _Float16  f16x8  __attribute__((ext_vector_type(8)));
typedef _Float16  f16x4  __attribute__((ext_vector_type(4)));
typedef float     f32x4  __attribute__((ext_vector_type(4)));

#if __has_builtin(__builtin_amdgcn_exp2f)
#define EXP2(x) __builtin_amdgcn_exp2f(x)
#else
#define EXP2(x) exp2f(x)
#endif

// Q is pre-scaled by 1/sqrt(64) * log2(e) so attention uses raw exp2.
#define QSCALE (0.125f * 1.44269504088896f)

// ---------------------------------------------------------------------------
// prep_all: blocks 0..511  : x -> fp16 X16 (same layout)
//           blocks 512..767: WT[n'][k] = fp16 transpose of [Wq|Wk]
//           blocks 768..775: Wvo[i][h] = sum_d Wv[i][h*64+d]*Wo[h*64+d], bvo
// ---------------------------------------------------------------------------
__global__ __launch_bounds__(256)
void prep_all(const float* __restrict__ x,
              const float* __restrict__ Wq, const float* __restrict__ Wk,
              const float* __restrict__ Wv, const float* __restrict__ bv,
              const float* __restrict__ Wo,
              _Float16* __restrict__ X16, _Float16* __restrict__ WT,
              float* __restrict__ Wvo, float* __restrict__ bvo) {
    __shared__ float smem[32 * 33];   // transpose tile / wo_s
    const int b = blockIdx.x;
    const int tid = threadIdx.x;

    if (b < 512) {
        // ---- x -> fp16 ----
        const size_t i4 = ((size_t)b * 256 + tid) * 4;
        const float4 v = *(const float4*)(x + i4);
        f16x4 o;
        o[0] = (_Float16)v.x; o[1] = (_Float16)v.y;
        o[2] = (_Float16)v.z; o[3] = (_Float16)v.w;
        *(f16x4*)(X16 + i4) = o;
    } else if (b < 768) {
        // ---- WT transpose via LDS 32x32 tile ----
        const int tb = b - 512;
        const int k0 = (tb & 7) * 32;        // k tile
        const int n0 = (tb >> 3) * 32;       // n' tile (never straddles 512)
        const float* W = (n0 < OUT) ? Wq : Wk;
        const int nc = (n0 < OUT) ? n0 : n0 - OUT;
        {
            const int row = tid >> 3;          // k within tile
            const int c4  = (tid & 7) * 4;     // n within tile
            const float4 v = *(const float4*)(W + (size_t)(k0 + row) * OUT + nc + c4);
            smem[row * 33 + c4 + 0] = v.x;
            smem[row * 33 + c4 + 1] = v.y;
            smem[row * 33 + c4 + 2] = v.z;
            smem[row * 33 + c4 + 3] = v.w;
        }
        __syncthreads();
        {
            const int nrow = tid >> 3;         // n within tile
            const int k4   = (tid & 7) * 4;    // k within tile
            f16x4 o;
            #pragma unroll
            for (int j = 0; j < 4; j++)
                o[j] = (_Float16)smem[(k4 + j) * 33 + nrow];
            *(f16x4*)(WT + (size_t)(n0 + nrow) * IN + k0 + k4) = o;
        }
    } else {
        // ---- prep_wvo ----
        float* wo_s = smem;
        wo_s[tid]       = Wo[tid];
        wo_s[tid + 256] = Wo[tid + 256];
        __syncthreads();
        const int i = (b - 768) * 32 + (tid >> 3);
        const int h = tid & 7;
        const float* wr = Wv + (size_t)i * OUT + h * HD;
        float s = 0.f;
        #pragma unroll
        for (int d = 0; d < HD; d += 4) {
            const float4 v = *(const float4*)(wr + d);
            s += v.x * wo_s[h * HD + d + 0] + v.y * wo_s[h * HD + d + 1]
               + v.z * wo_s[h * HD + d + 2] + v.w * wo_s[h * HD + d + 3];
        }
        Wvo[i * NH + h] = s;
        if (b == 768 && tid < NH) {
            float sb = 0.f;
            #pragma unroll
            for (int d = 0; d < HD; d++)
                sb += bv[tid * HD + d] * wo_s[tid * HD + d];
            bvo[tid] = sb;
        }
    }
}

// ---------------------------------------------------------------------------
// gemm_qk_vpm: blocks 0..1023: fp16 MFMA GEMM C = X16 @ WT^T, head-major
//   fp16 output [h][m][d] (Q scaled by QSCALE, +bias).
//   Retiled vs round-0: 32m x 64n per block (4 waves of 32m x 16n) ->
//   1024 blocks = 4 blocks/CU = 4 waves/SIMD for 2x latency hiding.
// blocks 1024..1087: vpmT[h][k] = sigmoid(mg(k)) * (x[k] @ Wvo[:,h] + bvo[h])
// ---------------------------------------------------------------------------
__global__ __launch_bounds__(256)
void gemm_qk_vpm(const _Float16* __restrict__ X16, const _Float16* __restrict__ WT,
                 const float* __restrict__ bq, const float* __restrict__ bk,
                 _Float16* __restrict__ Qh, _Float16* __restrict__ Kh,
                 const float* __restrict__ x, const float* __restrict__ rel_vel,
                 const float* __restrict__ rel_angle,
                 const float* __restrict__ Wmg1, const float* __restrict__ bmg1,
                 const float* __restrict__ Wmg2, const float* __restrict__ bmg2,
                 const float* __restrict__ Wvo, const float* __restrict__ bvo,
                 float* __restrict__ vpmT) {
    __shared__ _Float16 stage[32 * 68];   // gemm epilogue staging (4.25 KB)
    __shared__ float wvo_s[IN * NH];      // vpm weight cache (8 KB)
    const int tid = threadIdx.x;

    if (blockIdx.x >= 1024) {
        // ================= vpm branch =================
        #pragma unroll
        for (int i = 0; i < 8; i++) wvo_s[tid + 256 * i] = Wvo[tid + 256 * i];
        __syncthreads();

        const int k = (blockIdx.x - 1024) * 32 + (tid >> 3);
        const int h = tid & 7;

        const float m0 = rel_vel[k], m1 = rel_angle[k];
        float g = bmg2[0];
        #pragma unroll
        for (int j = 0; j < HD; j++) {
            float t = m0 * Wmg1[j] + m1 * Wmg1[HD + j] + bmg1[j];
            t = fmaxf(t, 0.f);
            g += t * Wmg2[j];
        }
        const float mg = 1.f / (1.f + __expf(-g));

        const float4* xr = (const float4*)(x + (size_t)k * IN);
        float a0 = 0.f, a1 = 0.f, a2 = 0.f, a3 = 0.f;
        #pragma unroll 4
        for (int i = 0; i < IN / 4; i++) {
            const float4 v = xr[i];
            a0 += v.x * wvo_s[(i * 4 + 0) * NH + h];
            a1 += v.y * wvo_s[(i * 4 + 1) * NH + h];
            a2 += v.z * wvo_s[(i * 4 + 2) * NH + h];
            a3 += v.w * wvo_s[(i * 4 + 3) * NH + h];
        }
        vpmT[h * N + k] = mg * (a0 + a1 + a2 + a3 + bvo[h]);
        return;
    }

    // ================= gemm branch =================
    const int lane  = tid & 63;
    const int wave  = tid >> 6;
    const int row16 = lane & 15;
    const int quad  = lane >> 4;
    const int gn = (blockIdx.x & 15) * 64;   // n' tile (one head, never straddles)
    const int mb = (blockIdx.x >> 4) * 32;   // m tile
    const bool isQ = (gn < OUT);             // block-uniform

    const size_t ar0 = (size_t)(mb + row16) * IN;
    const size_t ar1 = (size_t)(mb + 16 + row16) * IN;
    const _Float16* wrow = WT + (size_t)(gn + wave * 16 + row16) * IN;

    f32x4 acc[2] = {};
    for (int k0 = 0; k0 < IN; k0 += 32) {
        const int ko = k0 + quad * 8;
        const f16x8 a0 = *(const f16x8*)(X16 + ar0 + ko);
        const f16x8 a1 = *(const f16x8*)(X16 + ar1 + ko);
        const f16x8 bf = *(const f16x8*)(wrow + ko);
        acc[0] = __builtin_amdgcn_mfma_f32_16x16x32_f16(a0, bf, acc[0], 0, 0, 0);
        acc[1] = __builtin_amdgcn_mfma_f32_16x16x32_f16(a1, bf, acc[1], 0, 0, 0);
    }

    // stage into LDS (C layout: col n = lane&15, row m = quad*4+r)
    const float scale = isQ ? QSCALE : 1.0f;
    const int nl = wave * 16 + row16;              // 0..63
    const int nq = (isQ ? gn : gn - OUT) + nl;
    const float bias = isQ ? bq[nq] : bk[nq];
    #pragma unroll
    for (int mt = 0; mt < 2; mt++)
        #pragma unroll
        for (int r = 0; r < 4; r++) {
            const int ml = mt * 16 + quad * 4 + r; // 0..31
            stage[ml * 68 + nl] = (_Float16)((acc[mt][r] + bias) * scale);
        }
    __syncthreads();

    // write out: 32 rows x 64 f16 (one head), 8 chunks of 16B per row
    _Float16* dst = isQ ? Qh : Kh;
    const int h = (isQ ? gn : gn - OUT) >> 6;
    const int r = tid >> 3;            // 0..31
    const int c = tid & 7;             // 0..7
    const size_t goff = ((size_t)h * N + mb + r) * HD + c * 8;
    *(f16x8*)(dst + goff) = *(const f16x8*)(&stage[r * 68 + c * 8]);
}

// ---------------------------------------------------------------------------
// Attention partials, fp16 MFMA, A=K (streamed) / B=Q (64 q resident).
// Wave = 64 q x 128 k for one head; block = 4 waves; grid 1024:
// h = b&7 (XCD pin), then c (16) x qg (8).  4 blocks/CU -> 4 waves/SIMD.
// ---------------------------------------------------------------------------
__global__ __launch_bounds__(256)
void attn_mfma(const _Float16* __restrict__ Qh, const _Float16* __restrict__ Kh,
               const float* __restrict__ vpmT,
               float* __restrict__ pnum, float* __restrict__ pden) {
    const int b = blockIdx.x;
    const int h = b & 7;
    const int r = b >> 3;             // 0..127
    const int c = r >> 3;             // key chunk 0..15
    const int qg = r & 7;             // q-group 0..7
    const int lane = threadIdx.x & 63;
    const int wave = threadIdx.x >> 6;
    const int q0 = (qg * 4 + wave) * 64;
    const int row16 = lane & 15;
    const int quad  = lane >> 4;

    // B fragments (Q): B[n=lane&15][k=quad*8+j]; 4 q-tiles x 2 d-halves
    f16x8 Bq[4][2];
    #pragma unroll
    for (int qt = 0; qt < 4; qt++) {
        const size_t qoff = ((size_t)h * N + q0 + qt * 16 + row16) * HD + quad * 8;
        Bq[qt][0] = *(const f16x8*)(Qh + qoff);
        Bq[qt][1] = *(const f16x8*)(Qh + qoff + 32);
    }

    float num[4] = {}, den[4] = {};
    const int k0 = c * KPB;
    const size_t kbase = ((size_t)h * N + k0 + row16) * HD + quad * 8;
    const float* vp = vpmT + h * N + k0 + quad * 4;

    // register double-buffer the K tile + vpm
    f16x8 A0 = *(const f16x8*)(Kh + kbase);
    f16x8 A1 = *(const f16x8*)(Kh + kbase + 32);
    f32x4 vv = *(const f32x4*)(vp);

    #pragma unroll
    for (int t = 0; t < KT; t++) {
        const int tn = (t + 1 < KT) ? t + 1 : t;
        const size_t ka = kbase + (size_t)tn * 16 * HD;
        const f16x8 nA0 = *(const f16x8*)(Kh + ka);
        const f16x8 nA1 = *(const f16x8*)(Kh + ka + 32);
        const f32x4 nvv = *(const f32x4*)(vp + tn * 16);

        #pragma unroll
        for (int qt = 0; qt < 4; qt++) {
            f32x4 s = {0.f, 0.f, 0.f, 0.f};
            s = __builtin_amdgcn_mfma_f32_16x16x32_f16(A0, Bq[qt][0], s, 0, 0, 0);
            s = __builtin_amdgcn_mfma_f32_16x16x32_f16(A1, Bq[qt][1], s, 0, 0, 0);
            #pragma unroll
            for (int r4 = 0; r4 < 4; r4++) {
                const float e = EXP2(s[r4]);          // key = k0+t*16+quad*4+r4
                num[qt] += e * vv[r4];
                den[qt] += e;
            }
        }
        A0 = nA0; A1 = nA1; vv = nvv;
    }

    // reduce over quads (keys live on the quad dimension)
    #pragma unroll
    for (int qt = 0; qt < 4; qt++) {
        float n = num[qt], d = den[qt];
        n += __shfl_xor(n, 16, 64);  d += __shfl_xor(d, 16, 64);
        n += __shfl_xor(n, 32, 64);  d += __shfl_xor(d, 32, 64);
        if (quad == 0) {
            const int q = q0 + qt * 16 + row16;
            pnum[((size_t)c * NH + h) * N + q] = n;
            pden[((size_t)c * NH + h) * N + q] = d;
        }
    }
}

// ---------------------------------------------------------------------------
// finalize: out[q] = bo + sum_h (sum_c num) / (sum_c den)
// grid 8 x 256 (one thread per q); partial reads are coalesced across threads.
// ---------------------------------------------------------------------------
__global__ __launch_bounds__(256)
void finalize(const float* __restrict__ pnum, const float* __restrict__ pden,
              const float* __restrict__ bo, float* __restrict__ out) {
    const int q = blockIdx.x * 256 + threadIdx.x;
    float acc = bo[0];
    #pragma unroll
    for (int h = 0; h < NH; h++) {
        float num = 0.f, den = 0.f;
        #pragma unroll
        for (int ci = 0; ci < NC; ci++) {
            num += pnum[((size_t)ci * NH + h) * N + q];
            den += pden[((size_t)ci * NH + h) * N + q];
        }
        acc += num / den;
    }
    out[q] = acc;
}

// ---------------------------------------------------------------------------
extern "C" void kernel_launch(void* const* d_in, const int* in_sizes, int n_in,
                              void* d_out, int out_size, void* d_ws, size_t ws_size,
                              hipStream_t stream) {
    const float* x         = (const float*)d_in[0];
    // d_in[1] = rel_pos (unused: per-query bias cancels in softmax)
    const float* rel_vel   = (const float*)d_in[2];
    const float* rel_angle = (const float*)d_in[3];
    const float* Wq        = (const float*)d_in[4];
    const float* bq        = (const float*)d_in[5];
    const float* Wk        = (const float*)d_in[6];
    const float* bk        = (const float*)d_in[7];
    const float* Wv        = (const float*)d_in[8];
    const float* bv        = (const float*)d_in[9];
    // d_in[10..13] = Wsb1,bsb1,Wsb2,bsb2 (unused)
    const float* Wmg1      = (const float*)d_in[14];
    const float* bmg1      = (const float*)d_in[15];
    const float* Wmg2      = (const float*)d_in[16];
    const float* bmg2      = (const float*)d_in[17];
    const float* Wo        = (const float*)d_in[18];
    const float* bo        = (const float*)d_in[19];
    float* out = (float*)d_out;

    // workspace layout
    _Float16* X16 = (_Float16*)d_ws;                      // N*IN
    _Float16* WT  = X16 + (size_t)N * IN;                 // NQK*IN
    _Float16* Qh  = WT + (size_t)NQK * IN;                // [NH][N][HD]
    _Float16* Kh  = Qh + (size_t)NH * N * HD;
    float* fp     = (float*)(Kh + (size_t)NH * N * HD);
    float* Wvo    = fp;                          // IN*NH
    float* bvo    = Wvo + IN * NH;               // NH
    float* vpmT   = bvo + NH;                    // NH*N
    float* pnum   = vpmT + NH * N;               // NC*NH*N
    float* pden   = pnum + (size_t)NC * NH * N;  // NC*NH*N

    hipLaunchKernelGGL(prep_all, dim3(776), dim3(256), 0, stream,
                       x, Wq, Wk, Wv, bv, Wo, X16, WT, Wvo, bvo);
    hipLaunchKernelGGL(gemm_qk_vpm, dim3(1088), dim3(256), 0, stream,
                       X16, WT, bq, bk, Qh, Kh,
                       x, rel_vel, rel_angle, Wmg1, bmg1, Wmg2, bmg2, Wvo, bvo, vpmT);
    hipLaunchKernelGGL(attn_mfma, dim3(1024), dim3(256), 0, stream,
                       Qh, Kh, vpmT, pnum, pden);
    hipLaunchKernelGGL(finalize, dim3(8), dim3(256), 0, stream, pnum, pden, bo, out);
}

// Round 5
// 133.498 us; speedup vs baseline: 1.3126x; 1.0629x over previous
//
#include <hip/hip_runtime.h>
#include <hip/hip_bf16.h>

// Problem constants
constexpr int N    = 2048;
constexpr int IN   = 256;
constexpr int OUT  = 512;
constexpr int NH   = 8;
constexpr int HD   = 64;      // OUT / NH
constexpr int NQK  = 1024;    // Q|K concatenated columns
constexpr int NC   = 16;      // key chunks for attention
constexpr int KPB  = N / NC;  // 128 keys per chunk
constexpr int KT   = KPB / 16;// 8 key-tiles of 16

typedef _Float16  f16x8  __attribute__((ext_vector_type(8)));
typedef _Float16  f16x4  __attribute__((ext_vector_type(4)));
typedef float     f32x4  __attribute__((ext_vector_type(4)));

#if __has_builtin(__builtin_amdgcn_exp2f)
#define EXP2(x) __builtin_amdgcn_exp2f(x)
#else
#define EXP2(x) exp2f(x)
#endif

// Q is pre-scaled by 1/sqrt(64) * log2(e) so attention uses raw exp2.
#define QSCALE (0.125f * 1.44269504088896f)

// ---------------------------------------------------------------------------
// prep_all: blocks 0..511  : x -> fp16 X16 (same layout)
//           blocks 512..767: WT[n'][k] = fp16 transpose of [Wq|Wk]
//           blocks 768..775: Wvo[i][h] = sum_d Wv[i][h*64+d]*Wo[h*64+d], bvo
// ---------------------------------------------------------------------------
__global__ __launch_bounds__(256)
void prep_all(const float* __restrict__ x,
              const float* __restrict__ Wq, const float* __restrict__ Wk,
              const float* __restrict__ Wv, const float* __restrict__ bv,
              const float* __restrict__ Wo,
              _Float16* __restrict__ X16, _Float16* __restrict__ WT,
              float* __restrict__ Wvo, float* __restrict__ bvo) {
    __shared__ float smem[32 * 33];   // transpose tile / wo_s
    const int b = blockIdx.x;
    const int tid = threadIdx.x;

    if (b < 512) {
        // ---- x -> fp16 ----
        const size_t i4 = ((size_t)b * 256 + tid) * 4;
        const float4 v = *(const float4*)(x + i4);
        f16x4 o;
        o[0] = (_Float16)v.x; o[1] = (_Float16)v.y;
        o[2] = (_Float16)v.z; o[3] = (_Float16)v.w;
        *(f16x4*)(X16 + i4) = o;
    } else if (b < 768) {
        // ---- WT transpose via LDS 32x32 tile ----
        const int tb = b - 512;
        const int k0 = (tb & 7) * 32;        // k tile
        const int n0 = (tb >> 3) * 32;       // n' tile (never straddles 512)
        const float* W = (n0 < OUT) ? Wq : Wk;
        const int nc = (n0 < OUT) ? n0 : n0 - OUT;
        {
            const int row = tid >> 3;          // k within tile
            const int c4  = (tid & 7) * 4;     // n within tile
            const float4 v = *(const float4*)(W + (size_t)(k0 + row) * OUT + nc + c4);
            smem[row * 33 + c4 + 0] = v.x;
            smem[row * 33 + c4 + 1] = v.y;
            smem[row * 33 + c4 + 2] = v.z;
            smem[row * 33 + c4 + 3] = v.w;
        }
        __syncthreads();
        {
            const int nrow = tid >> 3;         // n within tile
            const int k4   = (tid & 7) * 4;    // k within tile
            f16x4 o;
            #pragma unroll
            for (int j = 0; j < 4; j++)
                o[j] = (_Float16)smem[(k4 + j) * 33 + nrow];
            *(f16x4*)(WT + (size_t)(n0 + nrow) * IN + k0 + k4) = o;
        }
    } else {
        // ---- prep_wvo ----
        float* wo_s = smem;
        wo_s[tid]       = Wo[tid];
        wo_s[tid + 256] = Wo[tid + 256];
        __syncthreads();
        const int i = (b - 768) * 32 + (tid >> 3);
        const int h = tid & 7;
        const float* wr = Wv + (size_t)i * OUT + h * HD;
        float s = 0.f;
        #pragma unroll
        for (int d = 0; d < HD; d += 4) {
            const float4 v = *(const float4*)(wr + d);
            s += v.x * wo_s[h * HD + d + 0] + v.y * wo_s[h * HD + d + 1]
               + v.z * wo_s[h * HD + d + 2] + v.w * wo_s[h * HD + d + 3];
        }
        Wvo[i * NH + h] = s;
        if (b == 768 && tid < NH) {
            float sb = 0.f;
            #pragma unroll
            for (int d = 0; d < HD; d++)
                sb += bv[tid * HD + d] * wo_s[tid * HD + d];
            bvo[tid] = sb;
        }
    }
}

// ---------------------------------------------------------------------------
// gemm_qk_vpm: blocks 0..511: fp16 MFMA GEMM C = X16 @ WT^T, head-major
//   fp16 output [h][m][d] (Q scaled by QSCALE, +bias).
// blocks 512..575: vpmT[h][k] = sigmoid(mg(k)) * (x[k] @ Wvo[:,h] + bvo[h])
// ---------------------------------------------------------------------------
__global__ __launch_bounds__(256)
void gemm_qk_vpm(const _Float16* __restrict__ X16, const _Float16* __restrict__ WT,
                 const float* __restrict__ bq, const float* __restrict__ bk,
                 _Float16* __restrict__ Qh, _Float16* __restrict__ Kh,
                 const float* __restrict__ x, const float* __restrict__ rel_vel,
                 const float* __restrict__ rel_angle,
                 const float* __restrict__ Wmg1, const float* __restrict__ bmg1,
                 const float* __restrict__ Wmg2, const float* __restrict__ bmg2,
                 const float* __restrict__ Wvo, const float* __restrict__ bvo,
                 float* __restrict__ vpmT) {
    __shared__ _Float16 stage[32 * 132];  // gemm epilogue staging
    __shared__ float wvo_s[IN * NH];      // vpm weight cache (8 KB)
    const int tid = threadIdx.x;

    if (blockIdx.x >= 512) {
        // ================= vpm branch =================
        #pragma unroll
        for (int i = 0; i < 8; i++) wvo_s[tid + 256 * i] = Wvo[tid + 256 * i];
        __syncthreads();

        const int k = (blockIdx.x - 512) * 32 + (tid >> 3);
        const int h = tid & 7;

        const float m0 = rel_vel[k], m1 = rel_angle[k];
        float g = bmg2[0];
        #pragma unroll
        for (int j = 0; j < HD; j++) {
            float t = m0 * Wmg1[j] + m1 * Wmg1[HD + j] + bmg1[j];
            t = fmaxf(t, 0.f);
            g += t * Wmg2[j];
        }
        const float mg = 1.f / (1.f + __expf(-g));

        const float4* xr = (const float4*)(x + (size_t)k * IN);
        float a0 = 0.f, a1 = 0.f, a2 = 0.f, a3 = 0.f;
        #pragma unroll 4
        for (int i = 0; i < IN / 4; i++) {
            const float4 v = xr[i];
            a0 += v.x * wvo_s[(i * 4 + 0) * NH + h];
            a1 += v.y * wvo_s[(i * 4 + 1) * NH + h];
            a2 += v.z * wvo_s[(i * 4 + 2) * NH + h];
            a3 += v.w * wvo_s[(i * 4 + 3) * NH + h];
        }
        vpmT[h * N + k] = mg * (a0 + a1 + a2 + a3 + bvo[h]);
        return;
    }

    // ================= gemm branch =================
    const int lane = tid & 63;
    const int wave = tid >> 6;
    const int row16 = lane & 15;
    const int quad  = lane >> 4;
    const int nb0 = (blockIdx.x & 7) * 128;
    const int mb  = (blockIdx.x >> 3) * 32;
    const int nb  = nb0 + wave * 32;

    const size_t ar[2] = {(size_t)(mb + row16) * IN, (size_t)(mb + 16 + row16) * IN};
    const size_t br[2] = {(size_t)(nb + row16) * IN, (size_t)(nb + 16 + row16) * IN};

    f32x4 acc[2][2] = {};
    for (int k0 = 0; k0 < IN; k0 += 32) {
        const int ko = k0 + quad * 8;
        f16x8 a[2], bf[2];
        #pragma unroll
        for (int t = 0; t < 2; t++) {
            a[t]  = *(const f16x8*)(X16 + ar[t] + ko);
            bf[t] = *(const f16x8*)(WT + br[t] + ko);
        }
        #pragma unroll
        for (int mt = 0; mt < 2; mt++)
            #pragma unroll
            for (int nt = 0; nt < 2; nt++)
                acc[mt][nt] = __builtin_amdgcn_mfma_f32_16x16x32_f16(a[mt], bf[nt], acc[mt][nt], 0, 0, 0);
    }

    // stage into LDS (C layout: col n = lane&15, row m = quad*4+r)
    const bool isQ = (nb0 < OUT);   // block-uniform
    const float scale = isQ ? QSCALE : 1.0f;
    #pragma unroll
    for (int mt = 0; mt < 2; mt++)
        #pragma unroll
        for (int nt = 0; nt < 2; nt++) {
            const int nl = wave * 32 + nt * 16 + row16;   // 0..127
            const int np = nb0 + nl;
            const int nq = isQ ? np : np - OUT;
            const float bias = isQ ? bq[nq] : bk[nq];
            #pragma unroll
            for (int r = 0; r < 4; r++) {
                const int ml = mt * 16 + quad * 4 + r;    // 0..31
                stage[ml * 132 + nl] = (_Float16)((acc[mt][nt][r] + bias) * scale);
            }
        }
    __syncthreads();

    // write out full lines: 64 rows (2 heads x 32 m) x 128B each
    _Float16* dst = isQ ? Qh : Kh;
    const int r2   = tid >> 2;         // 0..63
    const int cidx = tid & 3;          // 32B chunk
    const int hl   = r2 >> 5;          // head within block
    const int m    = r2 & 31;
    const int nqh  = (isQ ? nb0 : nb0 - OUT) + hl * 64;
    const int h    = nqh >> 6;
    const size_t goff = ((size_t)h * N + mb + m) * HD + cidx * 16;
    const int soff = m * 132 + hl * 64 + cidx * 16;
    *(f16x8*)(dst + goff)     = *(const f16x8*)(&stage[soff]);
    *(f16x8*)(dst + goff + 8) = *(const f16x8*)(&stage[soff + 8]);
}

// ---------------------------------------------------------------------------
// Attention partials, fp16 MFMA, A=K (streamed) / B=Q (64 q resident).
// Wave = 64 q x 128 k for one head; block = 4 waves; grid 1024:
// h = b&7 (XCD pin), then c (16) x qg (8).  4 blocks/CU -> 4 waves/SIMD.
// ---------------------------------------------------------------------------
__global__ __launch_bounds__(256)
void attn_mfma(const _Float16* __restrict__ Qh, const _Float16* __restrict__ Kh,
               const float* __restrict__ vpmT,
               float* __restrict__ pnum, float* __restrict__ pden) {
    const int b = blockIdx.x;
    const int h = b & 7;
    const int r = b >> 3;             // 0..127
    const int c = r >> 3;             // key chunk 0..15
    const int qg = r & 7;             // q-group 0..7
    const int lane = threadIdx.x & 63;
    const int wave = threadIdx.x >> 6;
    const int q0 = (qg * 4 + wave) * 64;
    const int row16 = lane & 15;
    const int quad  = lane >> 4;

    // B fragments (Q): B[n=lane&15][k=quad*8+j]; 4 q-tiles x 2 d-halves
    f16x8 Bq[4][2];
    #pragma unroll
    for (int qt = 0; qt < 4; qt++) {
        const size_t qoff = ((size_t)h * N + q0 + qt * 16 + row16) * HD + quad * 8;
        Bq[qt][0] = *(const f16x8*)(Qh + qoff);
        Bq[qt][1] = *(const f16x8*)(Qh + qoff + 32);
    }

    float num[4] = {}, den[4] = {};
    const int k0 = c * KPB;
    const size_t kbase = ((size_t)h * N + k0 + row16) * HD + quad * 8;
    const float* vp = vpmT + h * N + k0 + quad * 4;

    // register double-buffer the K tile + vpm
    f16x8 A0 = *(const f16x8*)(Kh + kbase);
    f16x8 A1 = *(const f16x8*)(Kh + kbase + 32);
    f32x4 vv = *(const f32x4*)(vp);

    #pragma unroll
    for (int t = 0; t < KT; t++) {
        const int tn = (t + 1 < KT) ? t + 1 : t;
        const size_t ka = kbase + (size_t)tn * 16 * HD;
        const f16x8 nA0 = *(const f16x8*)(Kh + ka);
        const f16x8 nA1 = *(const f16x8*)(Kh + ka + 32);
        const f32x4 nvv = *(const f32x4*)(vp + tn * 16);

        #pragma unroll
        for (int qt = 0; qt < 4; qt++) {
            f32x4 s = {0.f, 0.f, 0.f, 0.f};
            s = __builtin_amdgcn_mfma_f32_16x16x32_f16(A0, Bq[qt][0], s, 0, 0, 0);
            s = __builtin_amdgcn_mfma_f32_16x16x32_f16(A1, Bq[qt][1], s, 0, 0, 0);
            #pragma unroll
            for (int r4 = 0; r4 < 4; r4++) {
                const float e = EXP2(s[r4]);          // key = k0+t*16+quad*4+r4
                num[qt] += e * vv[r4];
                den[qt] += e;
            }
        }
        A0 = nA0; A1 = nA1; vv = nvv;
    }

    // reduce over quads (keys live on the quad dimension)
    #pragma unroll
    for (int qt = 0; qt < 4; qt++) {
        float n = num[qt], d = den[qt];
        n += __shfl_xor(n, 16, 64);  d += __shfl_xor(d, 16, 64);
        n += __shfl_xor(n, 32, 64);  d += __shfl_xor(d, 32, 64);
        if (quad == 0) {
            const int q = q0 + qt * 16 + row16;
            pnum[((size_t)c * NH + h) * N + q] = n;
            pden[((size_t)c * NH + h) * N + q] = d;
        }
    }
}

// ---------------------------------------------------------------------------
// finalize: out[q] = bo + sum_h (sum_c num) / (sum_c den)
// grid 8 x 256 (one thread per q); partial reads are coalesced across threads.
// ---------------------------------------------------------------------------
__global__ __launch_bounds__(256)
void finalize(const float* __restrict__ pnum, const float* __restrict__ pden,
              const float* __restrict__ bo, float* __restrict__ out) {
    const int q = blockIdx.x * 256 + threadIdx.x;
    float acc = bo[0];
    #pragma unroll
    for (int h = 0; h < NH; h++) {
        float num = 0.f, den = 0.f;
        #pragma unroll
        for (int ci = 0; ci < NC; ci++) {
            num += pnum[((size_t)ci * NH + h) * N + q];
            den += pden[((size_t)ci * NH + h) * N + q];
        }
        acc += num / den;
    }
    out[q] = acc;
}

// ---------------------------------------------------------------------------
extern "C" void kernel_launch(void* const* d_in, const int* in_sizes, int n_in,
                              void* d_out, int out_size, void* d_ws, size_t ws_size,
                              hipStream_t stream) {
    const float* x         = (const float*)d_in[0];
    // d_in[1] = rel_pos (unused: per-query bias cancels in softmax)
    const float* rel_vel   = (const float*)d_in[2];
    const float* rel_angle = (const float*)d_in[3];
    const float* Wq        = (const float*)d_in[4];
    const float* bq        = (const float*)d_in[5];
    const float* Wk        = (const float*)d_in[6];
    const float* bk        = (const float*)d_in[7];
    const float* Wv        = (const float*)d_in[8];
    const float* bv        = (const float*)d_in[9];
    // d_in[10..13] = Wsb1,bsb1,Wsb2,bsb2 (unused)
    const float* Wmg1      = (const float*)d_in[14];
    const float* bmg1      = (const float*)d_in[15];
    const float* Wmg2      = (const float*)d_in[16];
    const float* bmg2      = (const float*)d_in[17];
    const float* Wo        = (const float*)d_in[18];
    const float* bo        = (const float*)d_in[19];
    float* out = (float*)d_out;

    // workspace layout
    _Float16* X16 = (_Float16*)d_ws;                      // N*IN
    _Float16* WT  = X16 + (size_t)N * IN;                 // NQK*IN
    _Float16* Qh  = WT + (size_t)NQK * IN;                // [NH][N][HD]
    _Float16* Kh  = Qh + (size_t)NH * N * HD;
    float* fp     = (float*)(Kh + (size_t)NH * N * HD);
    float* Wvo    = fp;                          // IN*NH
    float* bvo    = Wvo + IN * NH;               // NH
    float* vpmT   = bvo + NH;                    // NH*N
    float* pnum   = vpmT + NH * N;               // NC*NH*N
    float* pden   = pnum + (size_t)NC * NH * N;  // NC*NH*N

    hipLaunchKernelGGL(prep_all, dim3(776), dim3(256), 0, stream,
                       x, Wq, Wk, Wv, bv, Wo, X16, WT, Wvo, bvo);
    hipLaunchKernelGGL(gemm_qk_vpm, dim3(576), dim3(256), 0, stream,
                       X16, WT, bq, bk, Qh, Kh,
                       x, rel_vel, rel_angle, Wmg1, bmg1, Wmg2, bmg2, Wvo, bvo, vpmT);
    hipLaunchKernelGGL(attn_mfma, dim3(1024), dim3(256), 0, stream,
                       Qh, Kh, vpmT, pnum, pden);
    hipLaunchKernelGGL(finalize, dim3(8), dim3(256), 0, stream, pnum, pden, bo, out);
}